// Round 5
// baseline (640.851 us; speedup 1.0000x reference)
//
#include <hip/hip_runtime.h>

#define N_NODES 50000
#define N_EDGES 1600000
#define NCHUNK  ((N_NODES + 255) / 256)   // 196
#define NN32    (N_NODES * 32)

typedef unsigned short ushort_t;
typedef _Float16 f16;
typedef __attribute__((ext_vector_type(8))) __bf16 bf16x8;
typedef __attribute__((ext_vector_type(4))) float  f32x4;

union FU { ushort_t s[8]; bf16x8 v; };

__device__ __forceinline__ float bf2f(ushort_t u) {
    union { unsigned int i; float f; } v; v.i = ((unsigned int)u) << 16; return v.f;
}
__device__ __forceinline__ ushort_t f2bf(float f) {
    union { float f; unsigned int i; } v; v.f = f;
    unsigned int r = v.i + 0x7fffu + ((v.i >> 16) & 1u);
    return (ushort_t)(r >> 16);
}
__device__ __forceinline__ float leaky(float x, float s) { return x >= 0.f ? x : s * x; }

// ---------------- K1: histogram of src ----------------
__global__ __launch_bounds__(256) void k_hist(const int* __restrict__ src, int* __restrict__ cnt) {
    int e = blockIdx.x * 256 + threadIdx.x;
    if (e < N_EDGES) atomicAdd(&cnt[src[e]], 1);
}

// ---------------- K2: exclusive scan of cnt -> cursor ----------------
__global__ __launch_bounds__(256) void k_scan_chunk(const int* __restrict__ cnt, int* __restrict__ cursor,
                                                    int* __restrict__ blocksum) {
    __shared__ int buf[256];
    int t = threadIdx.x, i = blockIdx.x * 256 + t;
    int v = (i < N_NODES) ? cnt[i] : 0;
    buf[t] = v; __syncthreads();
    for (int off = 1; off < 256; off <<= 1) {
        int x = (t >= off) ? buf[t - off] : 0;
        __syncthreads(); buf[t] += x; __syncthreads();
    }
    int incl = buf[t];
    if (i < N_NODES) cursor[i] = incl - v;
    if (t == 255) blocksum[blockIdx.x] = incl;
}
__global__ __launch_bounds__(256) void k_scan_block(int* __restrict__ blocksum) {
    __shared__ int buf[256];
    int t = threadIdx.x;
    int v = (t < NCHUNK) ? blocksum[t] : 0;
    buf[t] = v; __syncthreads();
    for (int off = 1; off < 256; off <<= 1) {
        int x = (t >= off) ? buf[t - off] : 0;
        __syncthreads(); buf[t] += x; __syncthreads();
    }
    blocksum[t] = buf[t] - v;   // exclusive
}
__global__ __launch_bounds__(256) void k_scan_add(int* __restrict__ cursor, const int* __restrict__ blocksum) {
    int i = blockIdx.x * 256 + threadIdx.x;
    if (i < N_NODES) cursor[i] += blocksum[i >> 8];
}

// ---------------- K3p: nid range-fill from rowptr (primary path) ----------------
__global__ __launch_bounds__(256) void k_fillnid(const int* __restrict__ cursor, const int* __restrict__ cnt,
                                                 int* __restrict__ nid) {
    int n = blockIdx.x * 256 + threadIdx.x;
    if (n < N_NODES) {
        int start = cursor[n], c = cnt[n];
        for (int i = 0; i < c; i++) nid[start + i] = n;
    }
}

// ---------------- K4p: fused edge MLP + CSR scatter of fp16 msg records (primary) ----------------
// 4 waves/block, wave handles 16 consecutive edges (original order -> coalesced ea reads).
__global__ __launch_bounds__(256) void k_mlp_scatter(
    const float* __restrict__ x_t, const float* __restrict__ edge_attr,
    const float* __restrict__ w1a, const float* __restrict__ b1a,
    const float* __restrict__ w2a, const float* __restrict__ b2a,
    const int* __restrict__ src, const int* __restrict__ tgt,
    int* __restrict__ cursor, f16* __restrict__ rec)
{
    __shared__ __align__(16) float h_lds[4][16][36];   // fp32 h slice, 144-B rows
    __shared__ __align__(16) f16   m_lds[4][16][40];   // fp16 msg rows, 80-B stride (16-B aligned)
    __shared__ int p_lds[4][16];
    const int t = threadIdx.x;
    const int w = t >> 6, L = t & 63, q = L >> 4, c = L & 15;

    bf16x8 B1[2], B2[2];
    #pragma unroll
    for (int h = 0; h < 2; h++) {
        FU u1, u2;
        #pragma unroll
        for (int j = 0; j < 8; j++) {
            int k = q * 8 + j, n = c + 16 * h;
            u1.s[j] = f2bf(w1a[k * 32 + n]);
            u2.s[j] = f2bf(w2a[k * 32 + n]);
        }
        B1[h] = u1.v; B2[h] = u2.v;
    }
    const float bias1[2] = { b1a[c], b1a[c + 16] };
    const float bias2[2] = { b2a[c], b2a[c + 16] };
    const f32x4 zero = { 0.f, 0.f, 0.f, 0.f };

    for (int cb = blockIdx.x; cb < N_EDGES / 64; cb += gridDim.x) {
        const int e = cb * 64 + w * 16 + c;
        if (q == 0) {
            int s = src[e];
            p_lds[w][c] = atomicAdd(&cursor[s], 1);
        }
        int tg = tgt[e];
        const float* gp = (q < 2) ? (x_t + (size_t)tg * 16 + q * 8)
                                  : (edge_attr + (size_t)e * 16 + (q - 2) * 8);
        FU af;
        #pragma unroll
        for (int j = 0; j < 8; j++) af.s[j] = f2bf(gp[j]);

        f32x4 a0 = __builtin_amdgcn_mfma_f32_16x16x32_bf16(af.v, B1[0], zero, 0, 0, 0);
        f32x4 a1 = __builtin_amdgcn_mfma_f32_16x16x32_bf16(af.v, B1[1], zero, 0, 0, 0);
        #pragma unroll
        for (int r = 0; r < 4; r++) {
            h_lds[w][q * 4 + r][c]      = leaky(a0[r] + bias1[0], 0.1f);
            h_lds[w][q * 4 + r][c + 16] = leaky(a1[r] + bias1[1], 0.1f);
        }
        __asm__ volatile("s_waitcnt lgkmcnt(0)" ::: "memory");

        float hv[8];
        __builtin_memcpy(&hv, &h_lds[w][c][q * 8], 32);
        FU hf;
        #pragma unroll
        for (int j = 0; j < 8; j++) hf.s[j] = f2bf(hv[j]);
        f32x4 m0 = __builtin_amdgcn_mfma_f32_16x16x32_bf16(hf.v, B2[0], zero, 0, 0, 0);
        f32x4 m1 = __builtin_amdgcn_mfma_f32_16x16x32_bf16(hf.v, B2[1], zero, 0, 0, 0);
        #pragma unroll
        for (int r = 0; r < 4; r++) {
            float m  = fminf(fmaxf(m0[r] + bias2[0], -60000.f), 60000.f);
            float n2 = fminf(fmaxf(m1[r] + bias2[1], -60000.f), 60000.f);
            m_lds[w][q * 4 + r][c]      = (f16)m;
            m_lds[w][q * 4 + r][c + 16] = (f16)n2;
        }
        __asm__ volatile("s_waitcnt lgkmcnt(0)" ::: "memory");

        // lane (q,c) writes 16-B chunk q of edge-row c's record -> one full 64-B line per record
        int p = p_lds[w][c];
        __builtin_memcpy((void*)(rec + (size_t)p * 32 + q * 8), &m_lds[w][c][q * 8], 16);
        // no __syncthreads: LDS slices wave-private; DS ops in-order per wave
    }
}

// ---------------- K5p: segmented moment reduction over CSR-ordered records (primary) ----------------
__global__ __launch_bounds__(256) void k_reduce(const f16* __restrict__ rec, const int* __restrict__ nid,
                                                float* __restrict__ S)
{
    __shared__ float msg_lds[4][16][33];
    __shared__ int   nid_lds[4][16];
    const int t = threadIdx.x;
    const int w = t >> 6, L = t & 63, q = L >> 4, c = L & 15;

    for (int cb = blockIdx.x; cb < N_EDGES / 64; cb += gridDim.x) {
        const int p = cb * 64 + w * 16 + c;
        if (q == 0) nid_lds[w][c] = nid[p];
        f16 chunk[8];
        __builtin_memcpy(&chunk, rec + (size_t)p * 32 + q * 8, 16);
        #pragma unroll
        for (int j = 0; j < 8; j++) msg_lds[w][c][q * 8 + j] = (float)chunk[j];
        __asm__ volatile("s_waitcnt lgkmcnt(0)" ::: "memory");

        // 64-lane scan: f = L&31 feature, hh = L>>5 half (rows hh*8 .. hh*8+7)
        const int f = L & 31, hh = L >> 5;
        float s1 = 0.f, s2 = 0.f, s3 = 0.f, s4 = 0.f;
        int cur = nid_lds[w][hh * 8];
        #pragma unroll
        for (int i = 0; i < 8; i++) {
            int row = hh * 8 + i;
            int nd = nid_lds[w][row];
            float m = msg_lds[w][row][f];
            if (nd != cur) {
                size_t b = (size_t)cur * 32 + f;
                unsafeAtomicAdd(S + b, s1);
                unsafeAtomicAdd(S + NN32 + b, s2);
                unsafeAtomicAdd(S + 2 * (size_t)NN32 + b, s3);
                unsafeAtomicAdd(S + 3 * (size_t)NN32 + b, s4);
                s1 = s2 = s3 = s4 = 0.f; cur = nd;
            }
            float mm = m * m;
            s1 += m; s2 += mm; s3 += mm * m; s4 += mm * mm;
        }
        size_t b = (size_t)cur * 32 + f;
        unsafeAtomicAdd(S + b, s1);
        unsafeAtomicAdd(S + NN32 + b, s2);
        unsafeAtomicAdd(S + 2 * (size_t)NN32 + b, s3);
        unsafeAtomicAdd(S + 3 * (size_t)NN32 + b, s4);
    }
}

// ---------------- K3f/K4f: round-4 fallback (proven, 54.8 MB footprint) ----------------
__global__ __launch_bounds__(256) void k_scatter4(const int* __restrict__ src, const int* __restrict__ tgt,
                                                  int* __restrict__ cursor, int4* __restrict__ meta) {
    int e = blockIdx.x * 256 + threadIdx.x;
    if (e < N_EDGES) {
        int s = src[e], tg = tgt[e];
        int p = atomicAdd(&cursor[s], 1);
        if (p >= 0 && p < N_EDGES) meta[p] = make_int4(e, s, tg, 0);
    }
}

__global__ __launch_bounds__(256) void k_msg4(
    const float* __restrict__ x_t, const float* __restrict__ edge_attr,
    const float* __restrict__ w1a, const float* __restrict__ b1a,
    const float* __restrict__ w2a, const float* __restrict__ b2a,
    const int4* __restrict__ meta, float* __restrict__ S)
{
    __shared__ __align__(16) float h_lds[4][16][36];
    __shared__ float msg_lds[4][16][33];
    __shared__ int   nid_lds[4][16];
    const int t = threadIdx.x;
    const int w = t >> 6, L = t & 63, q = L >> 4, c = L & 15;

    bf16x8 B1[2], B2[2];
    #pragma unroll
    for (int h = 0; h < 2; h++) {
        FU u1, u2;
        #pragma unroll
        for (int j = 0; j < 8; j++) {
            int k = q * 8 + j, n = c + 16 * h;
            u1.s[j] = f2bf(w1a[k * 32 + n]);
            u2.s[j] = f2bf(w2a[k * 32 + n]);
        }
        B1[h] = u1.v; B2[h] = u2.v;
    }
    const float bias1[2] = { b1a[c], b1a[c + 16] };
    const float bias2[2] = { b2a[c], b2a[c + 16] };
    const f32x4 zero = { 0.f, 0.f, 0.f, 0.f };

    for (int cb = blockIdx.x; cb < N_EDGES / 64; cb += gridDim.x) {
        const int B0 = cb * 64;
        const int p  = B0 + w * 16 + c;
        int4 md = meta[p];
        if (q == 0) nid_lds[w][c] = md.y;
        const float* gp = (q < 2) ? (x_t + (size_t)md.z * 16 + q * 8)
                                  : (edge_attr + (size_t)md.x * 16 + (q - 2) * 8);
        FU af;
        #pragma unroll
        for (int j = 0; j < 8; j++) af.s[j] = f2bf(gp[j]);
        f32x4 a0 = __builtin_amdgcn_mfma_f32_16x16x32_bf16(af.v, B1[0], zero, 0, 0, 0);
        f32x4 a1 = __builtin_amdgcn_mfma_f32_16x16x32_bf16(af.v, B1[1], zero, 0, 0, 0);
        #pragma unroll
        for (int r = 0; r < 4; r++) {
            h_lds[w][q * 4 + r][c]      = leaky(a0[r] + bias1[0], 0.1f);
            h_lds[w][q * 4 + r][c + 16] = leaky(a1[r] + bias1[1], 0.1f);
        }
        __asm__ volatile("s_waitcnt lgkmcnt(0)" ::: "memory");
        float hv[8];
        __builtin_memcpy(&hv, &h_lds[w][c][q * 8], 32);
        FU hf;
        #pragma unroll
        for (int j = 0; j < 8; j++) hf.s[j] = f2bf(hv[j]);
        f32x4 m0 = __builtin_amdgcn_mfma_f32_16x16x32_bf16(hf.v, B2[0], zero, 0, 0, 0);
        f32x4 m1 = __builtin_amdgcn_mfma_f32_16x16x32_bf16(hf.v, B2[1], zero, 0, 0, 0);
        #pragma unroll
        for (int r = 0; r < 4; r++) {
            float m  = fminf(fmaxf(m0[r] + bias2[0], -1e6f), 1e6f);
            float n2 = fminf(fmaxf(m1[r] + bias2[1], -1e6f), 1e6f);
            msg_lds[w][q * 4 + r][c]      = m;
            msg_lds[w][q * 4 + r][c + 16] = n2;
        }
        __asm__ volatile("s_waitcnt lgkmcnt(0)" ::: "memory");
        if (L < 32) {
            const int f = L;
            float s1 = 0.f, s2 = 0.f, s3 = 0.f, s4 = 0.f;
            int cur = nid_lds[w][0];
            #pragma unroll
            for (int i = 0; i < 16; i++) {
                int nd = nid_lds[w][i];
                float m = msg_lds[w][i][f];
                if (nd != cur) {
                    size_t b = (size_t)cur * 32 + f;
                    unsafeAtomicAdd(S + b, s1);
                    unsafeAtomicAdd(S + NN32 + b, s2);
                    unsafeAtomicAdd(S + 2 * (size_t)NN32 + b, s3);
                    unsafeAtomicAdd(S + 3 * (size_t)NN32 + b, s4);
                    s1 = s2 = s3 = s4 = 0.f; cur = nd;
                }
                float mm = m * m;
                s1 += m; s2 += mm; s3 += mm * m; s4 += mm * mm;
            }
            size_t b = (size_t)cur * 32 + f;
            unsafeAtomicAdd(S + b, s1);
            unsafeAtomicAdd(S + NN32 + b, s2);
            unsafeAtomicAdd(S + 2 * (size_t)NN32 + b, s3);
            unsafeAtomicAdd(S + 3 * (size_t)NN32 + b, s4);
        }
    }
}

// ---------------- K6: node features -> h_cat (bf16 [N,160]) ----------------
__global__ __launch_bounds__(256) void k_feat(
    const int* __restrict__ cnt, const float* __restrict__ S,
    const float* __restrict__ x_s, const float* __restrict__ u,
    ushort_t* __restrict__ hcat, float* __restrict__ bnsum)
{
    if (blockIdx.x == 0 && threadIdx.x < 32) bnsum[threadIdx.x] = 0.f;
    int idx = blockIdx.x * 256 + threadIdx.x;
    int n = idx >> 5, f = idx & 31;
    float cv = (float)cnt[n];
    float denom = fmaxf(cv, 1.f);
    float s1 = S[(size_t)0 * NN32 + n * 32 + f];
    float s2 = S[(size_t)1 * NN32 + n * 32 + f];
    float s3 = S[(size_t)2 * NN32 + n * 32 + f];
    float s4 = S[(size_t)3 * NN32 + n * 32 + f];
    float mean = s1 / denom;
    float m2r = s2 / denom, m3r = s3 / denom, m4r = s4 / denom;
    float var0 = m2r - mean * mean;
    float var = leaky(var0, 0.01f);
    float stdv = sqrtf(var + 1e-6f);
    float e3 = m3r - 3.f * mean * m2r + 2.f * mean * mean * mean;
    float skew = e3 / (stdv * stdv * stdv);
    float e4 = m4r - 4.f * mean * m3r + 6.f * mean * mean * m2r - 3.f * mean * mean * mean * mean;
    float kurt = e4 / (stdv * stdv * stdv * stdv);
    size_t base = (size_t)n * 160;
    hcat[base + 16 + f]  = f2bf(mean);
    hcat[base + 48 + f]  = f2bf(stdv);
    hcat[base + 80 + f]  = f2bf(skew);
    hcat[base + 112 + f] = f2bf(kurt);
    if (f < 16) {
        hcat[base + f]       = f2bf(x_s[(size_t)n * 16 + f]);
        hcat[base + 144 + f] = f2bf(u[f]);
    }
}

// ---------------- K7: GEMM1 [N,160]@[160,160] + bias + leaky -> h2 (bf16) ----------------
__global__ __launch_bounds__(256) void k_gemm1(const ushort_t* __restrict__ hcat,
                                               const float* __restrict__ w1b,
                                               const float* __restrict__ b1b,
                                               ushort_t* __restrict__ h2)
{
    __shared__ __align__(16) ushort_t W1T[160 * 168];
    int t = threadIdx.x;
    for (int i = t; i < 160 * 160; i += 256) { int k = i / 160, n = i % 160; W1T[n * 168 + k] = f2bf(w1b[i]); }
    __syncthreads();
    int w = t >> 6, L = t & 63, q = L >> 4, c = L & 15;
    const f32x4 zero = { 0.f, 0.f, 0.f, 0.f };
    for (int tile = blockIdx.x * 4 + w; tile < 3125 * 10; tile += gridDim.x * 4) {
        int rt = tile / 10, nt = tile % 10;
        int m = rt * 16 + c, n = nt * 16 + c;
        f32x4 acc = zero;
        #pragma unroll
        for (int ks = 0; ks < 5; ks++) {
            bf16x8 a; __builtin_memcpy(&a, hcat + (size_t)m * 160 + ks * 32 + q * 8, 16);
            bf16x8 b; __builtin_memcpy(&b, &W1T[n * 168 + ks * 32 + q * 8], 16);
            acc = __builtin_amdgcn_mfma_f32_16x16x32_bf16(a, b, acc, 0, 0, 0);
        }
        float bias = b1b[n];
        #pragma unroll
        for (int r = 0; r < 4; r++) {
            h2[(size_t)(rt * 16 + q * 4 + r) * 160 + n] = f2bf(leaky(acc[r] + bias, 0.1f));
        }
    }
}

// ---------------- K8: GEMM2 [N,160]@[160,16] + bias -> outpre (fp32) + BN partials ----------------
__global__ __launch_bounds__(256) void k_gemm2(const ushort_t* __restrict__ h2,
                                               const float* __restrict__ w2b,
                                               const float* __restrict__ b2b,
                                               float* __restrict__ outpre, float* __restrict__ bnsum)
{
    __shared__ __align__(16) ushort_t W2T[16 * 168];
    int t = threadIdx.x;
    for (int i = t; i < 160 * 16; i += 256) { int k = i / 16, n = i % 16; W2T[n * 168 + k] = f2bf(w2b[i]); }
    __syncthreads();
    int w = t >> 6, L = t & 63, q = L >> 4, c = L & 15;
    const f32x4 zero = { 0.f, 0.f, 0.f, 0.f };
    float ps = 0.f, ps2 = 0.f;
    float bias = b2b[c];
    for (int rt = blockIdx.x * 4 + w; rt < 3125; rt += gridDim.x * 4) {
        int m = rt * 16 + c;
        f32x4 acc = zero;
        #pragma unroll
        for (int ks = 0; ks < 5; ks++) {
            bf16x8 a; __builtin_memcpy(&a, h2 + (size_t)m * 160 + ks * 32 + q * 8, 16);
            bf16x8 b; __builtin_memcpy(&b, &W2T[c * 168 + ks * 32 + q * 8], 16);
            acc = __builtin_amdgcn_mfma_f32_16x16x32_bf16(a, b, acc, 0, 0, 0);
        }
        #pragma unroll
        for (int r = 0; r < 4; r++) {
            float v = acc[r] + bias;
            outpre[(size_t)(rt * 16 + q * 4 + r) * 16 + c] = v;
            ps += v; ps2 += v * v;
        }
    }
    ps  += __shfl_xor(ps, 16);  ps  += __shfl_xor(ps, 32);
    ps2 += __shfl_xor(ps2, 16); ps2 += __shfl_xor(ps2, 32);
    if (q == 0) {
        unsafeAtomicAdd(&bnsum[c], ps);
        unsafeAtomicAdd(&bnsum[16 + c], ps2);
    }
}

// ---------------- K9: BatchNorm apply -> d_out (fp32) ----------------
__global__ __launch_bounds__(256) void k_bn(const float* __restrict__ outpre, const float* __restrict__ bnsum,
                                            const float* __restrict__ gamma, const float* __restrict__ beta,
                                            float* __restrict__ out)
{
    int i = blockIdx.x * 256 + threadIdx.x;
    int c = i & 15;
    float x = outpre[i];
    float mu = bnsum[c] * (1.f / N_NODES);
    float var = bnsum[16 + c] * (1.f / N_NODES) - mu * mu;
    out[i] = gamma[c] * (x - mu) * rsqrtf(var + 1e-5f) + beta[c];
}

// ---------------- launch ----------------
extern "C" void kernel_launch(void* const* d_in, const int* in_sizes, int n_in,
                              void* d_out, int out_size, void* d_ws, size_t ws_size,
                              hipStream_t stream) {
    const float* x_s  = (const float*)d_in[0];
    const float* x_t  = (const float*)d_in[1];
    const float* ea   = (const float*)d_in[2];
    const float* u    = (const float*)d_in[3];
    const float* w1a  = (const float*)d_in[4];
    const float* b1a  = (const float*)d_in[5];
    const float* w2a  = (const float*)d_in[6];
    const float* b2a  = (const float*)d_in[7];
    const float* w1b  = (const float*)d_in[8];
    const float* b1b  = (const float*)d_in[9];
    const float* w2b  = (const float*)d_in[10];
    const float* b2b  = (const float*)d_in[11];
    const float* gam  = (const float*)d_in[12];
    const float* bet  = (const float*)d_in[13];
    const int* eidx   = (const int*)d_in[14];
    const int* src = eidx;
    const int* tgt = eidx + N_EDGES;

    char* ws = (char*)d_ws;
    // Shared in both paths: S [0,25.6M) zeroed, cnt [25.6M, 25,800,192) zeroed, h2 overlays S.
    const size_t OFF_S      = 0;
    const size_t OFF_CNT    = 25600000;
    const size_t ZERO_BYTES = 25800192;
    const size_t OFF_H2     = 0;

    // Primary (staged) layout — needs 138,001,536 B:
    //   rec    [25,800,192, 128,200,192) fp16[1.6M*32]
    //   nid    [128,200,192, 134,600,192) int[1.6M]
    //   cursor [134,600,192, 134,800,384)
    //   blksum [134,800,384, 134,801,408)
    //   bnsum  [134,801,408, 134,801,536)
    //   outpre [134,801,536, 138,001,536)
    //   hcat overlays rec (rec dead after k_reduce)
    const size_t WS_FULL = 138001536;
    // Fallback (round-4) layout — 54,801,536 B (proven to fit):
    //   meta [25,800,192, 51,400,192), cursor [51,400,192, ..), blksum, bnsum, outpre, hcat overlays meta.
    const bool staged = (ws_size >= WS_FULL);

    float* S   = (float*)(ws + OFF_S);
    int*   cnt = (int*)(ws + OFF_CNT);
    ushort_t* h2 = (ushort_t*)(ws + OFF_H2);

    size_t off_cursor = staged ? 134600192u : 51400192u;
    size_t off_blksum = staged ? 134800384u : 51600384u;
    size_t off_bnsum  = staged ? 134801408u : 51601408u;
    size_t off_outpre = staged ? 134801536u : 51601536u;
    size_t off_hcat   = 25800192u;   // overlays rec (staged) or meta (fallback)

    int*   cursor  = (int*)(ws + off_cursor);
    int*   blksum  = (int*)(ws + off_blksum);
    float* bnsum   = (float*)(ws + off_bnsum);
    float* outpre  = (float*)(ws + off_outpre);
    ushort_t* hcat = (ushort_t*)(ws + off_hcat);
    f16*   rec     = (f16*)(ws + 25800192u);
    int*   nid     = (int*)(ws + 128200192u);
    int4*  meta    = (int4*)(ws + 25800192u);

    hipMemsetAsync(ws, 0, ZERO_BYTES, stream);

    k_hist<<<(N_EDGES + 255) / 256, 256, 0, stream>>>(src, cnt);
    k_scan_chunk<<<NCHUNK, 256, 0, stream>>>(cnt, cursor, blksum);
    k_scan_block<<<1, 256, 0, stream>>>(blksum);
    k_scan_add<<<NCHUNK, 256, 0, stream>>>(cursor, blksum);

    if (staged) {
        k_fillnid<<<NCHUNK, 256, 0, stream>>>(cursor, cnt, nid);
        k_mlp_scatter<<<2048, 256, 0, stream>>>(x_t, ea, w1a, b1a, w2a, b2a, src, tgt, cursor, rec);
        k_reduce<<<1792, 256, 0, stream>>>(rec, nid, S);
    } else {
        k_scatter4<<<(N_EDGES + 255) / 256, 256, 0, stream>>>(src, tgt, cursor, meta);
        k_msg4<<<1792, 256, 0, stream>>>(x_t, ea, w1a, b1a, w2a, b2a, meta, S);
    }

    k_feat<<<(N_NODES * 32) / 256, 256, 0, stream>>>(cnt, S, x_s, u, hcat, bnsum);
    k_gemm1<<<1024, 256, 0, stream>>>(hcat, w1b, b1b, h2);
    k_gemm2<<<512, 256, 0, stream>>>(h2, w2b, b2b, outpre, bnsum);
    k_bn<<<(N_NODES * 16) / 256, 256, 0, stream>>>(outpre, bnsum, gam, bet, (float*)d_out);
}

// Round 7
// 506.888 us; speedup vs baseline: 1.2643x; 1.2643x over previous
//
#include <hip/hip_runtime.h>

#define N_NODES 50000
#define N_EDGES 1600000
#define NCHUNK  ((N_NODES + 255) / 256)   // 196

typedef unsigned short ushort_t;
typedef _Float16 f16;
typedef __attribute__((ext_vector_type(8))) __bf16 bf16x8;
typedef __attribute__((ext_vector_type(4))) float  f32x4;

union FU { ushort_t s[8]; bf16x8 v; };

__device__ __forceinline__ float bf2f(ushort_t u) {
    union { unsigned int i; float f; } v; v.i = ((unsigned int)u) << 16; return v.f;
}
__device__ __forceinline__ ushort_t f2bf(float f) {
    union { float f; unsigned int i; } v; v.f = f;
    unsigned int r = v.i + 0x7fffu + ((v.i >> 16) & 1u);
    return (ushort_t)(r >> 16);
}
__device__ __forceinline__ float leaky(float x, float s) { return x >= 0.f ? x : s * x; }

// ---------------- K1: histogram of src ----------------
__global__ __launch_bounds__(256) void k_hist(const int* __restrict__ src, int* __restrict__ cnt) {
    int e = blockIdx.x * 256 + threadIdx.x;
    if (e < N_EDGES) atomicAdd(&cnt[src[e]], 1);
}

// ---------------- K2: exclusive scan of cnt -> cursor (+rowptr copy) ----------------
__global__ __launch_bounds__(256) void k_scan_chunk(const int* __restrict__ cnt, int* __restrict__ cursor,
                                                    int* __restrict__ blocksum) {
    __shared__ int buf[256];
    int t = threadIdx.x, i = blockIdx.x * 256 + t;
    int v = (i < N_NODES) ? cnt[i] : 0;
    buf[t] = v; __syncthreads();
    for (int off = 1; off < 256; off <<= 1) {
        int x = (t >= off) ? buf[t - off] : 0;
        __syncthreads(); buf[t] += x; __syncthreads();
    }
    int incl = buf[t];
    if (i < N_NODES) cursor[i] = incl - v;
    if (t == 255) blocksum[blockIdx.x] = incl;
}
__global__ __launch_bounds__(256) void k_scan_block(int* __restrict__ blocksum) {
    __shared__ int buf[256];
    int t = threadIdx.x;
    int v = (t < NCHUNK) ? blocksum[t] : 0;
    buf[t] = v; __syncthreads();
    for (int off = 1; off < 256; off <<= 1) {
        int x = (t >= off) ? buf[t - off] : 0;
        __syncthreads(); buf[t] += x; __syncthreads();
    }
    blocksum[t] = buf[t] - v;   // exclusive
}
__global__ __launch_bounds__(256) void k_scan_add(int* __restrict__ cursor, const int* __restrict__ blocksum,
                                                  int* __restrict__ rowptr) {
    int i = blockIdx.x * 256 + threadIdx.x;
    if (i < N_NODES) {
        int v = cursor[i] + blocksum[i >> 8];
        cursor[i] = v;
        rowptr[i] = v;     // persistent copy (cursor is consumed by k_mlp_scatter)
    }
}

// ---------------- K3: fused edge MLP + CSR scatter of fp16 msg records ----------------
// 4 waves/block, wave handles 16 consecutive edges (original order -> coalesced ea reads).
// Record = 32 fp16 = 64 B = exactly one HBM line; 4 lanes write 16-B chunks -> full-line store.
__global__ __launch_bounds__(256) void k_mlp_scatter(
    const float* __restrict__ x_t, const float* __restrict__ edge_attr,
    const float* __restrict__ w1a, const float* __restrict__ b1a,
    const float* __restrict__ w2a, const float* __restrict__ b2a,
    const int* __restrict__ src, const int* __restrict__ tgt,
    int* __restrict__ cursor, f16* __restrict__ rec)
{
    __shared__ __align__(16) float h_lds[4][16][36];   // fp32 h slice, 144-B rows
    __shared__ __align__(16) f16   m_lds[4][16][40];   // fp16 msg rows, 80-B stride
    __shared__ int p_lds[4][16];
    const int t = threadIdx.x;
    const int w = t >> 6, L = t & 63, q = L >> 4, c = L & 15;

    bf16x8 B1[2], B2[2];
    #pragma unroll
    for (int h = 0; h < 2; h++) {
        FU u1, u2;
        #pragma unroll
        for (int j = 0; j < 8; j++) {
            int k = q * 8 + j, n = c + 16 * h;
            u1.s[j] = f2bf(w1a[k * 32 + n]);
            u2.s[j] = f2bf(w2a[k * 32 + n]);
        }
        B1[h] = u1.v; B2[h] = u2.v;
    }
    const float bias1[2] = { b1a[c], b1a[c + 16] };
    const float bias2[2] = { b2a[c], b2a[c + 16] };
    const f32x4 zero = { 0.f, 0.f, 0.f, 0.f };

    for (int cb = blockIdx.x; cb < N_EDGES / 64; cb += gridDim.x) {
        const int e = cb * 64 + w * 16 + c;
        if (q == 0) {
            int s = src[e];
            p_lds[w][c] = atomicAdd(&cursor[s], 1);
        }
        int tg = tgt[e];
        const float* gp = (q < 2) ? (x_t + (size_t)tg * 16 + q * 8)
                                  : (edge_attr + (size_t)e * 16 + (q - 2) * 8);
        FU af;
        #pragma unroll
        for (int j = 0; j < 8; j++) af.s[j] = f2bf(gp[j]);

        f32x4 a0 = __builtin_amdgcn_mfma_f32_16x16x32_bf16(af.v, B1[0], zero, 0, 0, 0);
        f32x4 a1 = __builtin_amdgcn_mfma_f32_16x16x32_bf16(af.v, B1[1], zero, 0, 0, 0);
        #pragma unroll
        for (int r = 0; r < 4; r++) {
            h_lds[w][q * 4 + r][c]      = leaky(a0[r] + bias1[0], 0.1f);
            h_lds[w][q * 4 + r][c + 16] = leaky(a1[r] + bias1[1], 0.1f);
        }
        __asm__ volatile("s_waitcnt lgkmcnt(0)" ::: "memory");

        float hv[8];
        __builtin_memcpy(&hv, &h_lds[w][c][q * 8], 32);
        FU hf;
        #pragma unroll
        for (int j = 0; j < 8; j++) hf.s[j] = f2bf(hv[j]);
        f32x4 m0 = __builtin_amdgcn_mfma_f32_16x16x32_bf16(hf.v, B2[0], zero, 0, 0, 0);
        f32x4 m1 = __builtin_amdgcn_mfma_f32_16x16x32_bf16(hf.v, B2[1], zero, 0, 0, 0);
        #pragma unroll
        for (int r = 0; r < 4; r++) {
            float m  = fminf(fmaxf(m0[r] + bias2[0], -60000.f), 60000.f);
            float n2 = fminf(fmaxf(m1[r] + bias2[1], -60000.f), 60000.f);
            m_lds[w][q * 4 + r][c]      = (f16)m;
            m_lds[w][q * 4 + r][c + 16] = (f16)n2;
        }
        __asm__ volatile("s_waitcnt lgkmcnt(0)" ::: "memory");

        int p = p_lds[w][c];
        f32x4 chunk;
        __builtin_memcpy(&chunk, &m_lds[w][c][q * 8], 16);
        __builtin_nontemporal_store(chunk, (f32x4*)(rec + (size_t)p * 32 + q * 8));
        // no __syncthreads: LDS slices wave-private; DS ops in-order per wave
    }
}

// ---------------- K4: per-node moment reduce + feature build (NO atomics) ----------------
// Wave per node: node's records are CONTIGUOUS in rec after CSR scatter.
// lane = (f, h): f = feature 0..31, h = edge-parity half; shfl_xor(32) combines halves.
__global__ __launch_bounds__(256) void k_node(
    const f16* __restrict__ rec, const int* __restrict__ rowptr, const int* __restrict__ cnt,
    const float* __restrict__ x_s, const float* __restrict__ u,
    ushort_t* __restrict__ hcat, float* __restrict__ bnsum)
{
    if (blockIdx.x == 0 && threadIdx.x < 32) bnsum[threadIdx.x] = 0.f;
    const int t = threadIdx.x, w = t >> 6, L = t & 63;
    const int n = blockIdx.x * 4 + w;             // grid = 12500 blocks exactly
    const int f = L & 31, h = L >> 5;
    const int start = rowptr[n], d = cnt[n];

    float s1 = 0.f, s2 = 0.f, s3 = 0.f, s4 = 0.f;
    for (int i = h; i < d; i += 2) {
        float m = (float)rec[(size_t)(start + i) * 32 + f];
        float mm = m * m;
        s1 += m; s2 += mm; s3 += mm * m; s4 += mm * mm;
    }
    s1 += __shfl_xor(s1, 32); s2 += __shfl_xor(s2, 32);
    s3 += __shfl_xor(s3, 32); s4 += __shfl_xor(s4, 32);

    const size_t base = (size_t)n * 160;
    if (L < 32) {
        float denom = fmaxf((float)d, 1.f);
        float mean = s1 / denom;
        float m2r = s2 / denom, m3r = s3 / denom, m4r = s4 / denom;
        float var0 = m2r - mean * mean;
        float var = leaky(var0, 0.01f);
        float stdv = sqrtf(var + 1e-6f);
        float e3 = m3r - 3.f * mean * m2r + 2.f * mean * mean * mean;
        float skew = e3 / (stdv * stdv * stdv);
        float e4 = m4r - 4.f * mean * m3r + 6.f * mean * mean * m2r
                   - 3.f * mean * mean * mean * mean;
        float kurt = e4 / (stdv * stdv * stdv * stdv);
        hcat[base + 16 + f]  = f2bf(mean);
        hcat[base + 48 + f]  = f2bf(stdv);
        hcat[base + 80 + f]  = f2bf(skew);
        hcat[base + 112 + f] = f2bf(kurt);
    }
    if (L < 16) {
        hcat[base + L]       = f2bf(x_s[(size_t)n * 16 + L]);
        hcat[base + 144 + L] = f2bf(u[L]);
    }
}

// ---------------- K5: GEMM1 [N,160]@[160,160] + bias + leaky -> h2 (bf16) ----------------
__global__ __launch_bounds__(256) void k_gemm1(const ushort_t* __restrict__ hcat,
                                               const float* __restrict__ w1b,
                                               const float* __restrict__ b1b,
                                               ushort_t* __restrict__ h2)
{
    __shared__ __align__(16) ushort_t W1T[160 * 168];
    int t = threadIdx.x;
    for (int i = t; i < 160 * 160; i += 256) { int k = i / 160, n = i % 160; W1T[n * 168 + k] = f2bf(w1b[i]); }
    __syncthreads();
    int w = t >> 6, L = t & 63, q = L >> 4, c = L & 15;
    const f32x4 zero = { 0.f, 0.f, 0.f, 0.f };
    for (int tile = blockIdx.x * 4 + w; tile < 3125 * 10; tile += gridDim.x * 4) {
        int rt = tile / 10, nt = tile % 10;
        int m = rt * 16 + c, n = nt * 16 + c;
        f32x4 acc = zero;
        #pragma unroll
        for (int ks = 0; ks < 5; ks++) {
            bf16x8 a; __builtin_memcpy(&a, hcat + (size_t)m * 160 + ks * 32 + q * 8, 16);
            bf16x8 b; __builtin_memcpy(&b, &W1T[n * 168 + ks * 32 + q * 8], 16);
            acc = __builtin_amdgcn_mfma_f32_16x16x32_bf16(a, b, acc, 0, 0, 0);
        }
        float bias = b1b[n];
        #pragma unroll
        for (int r = 0; r < 4; r++) {
            h2[(size_t)(rt * 16 + q * 4 + r) * 160 + n] = f2bf(leaky(acc[r] + bias, 0.1f));
        }
    }
}

// ---------------- K6: GEMM2 [N,160]@[160,16] + bias -> outpre (fp32) + BN partials ----------------
__global__ __launch_bounds__(256) void k_gemm2(const ushort_t* __restrict__ h2,
                                               const float* __restrict__ w2b,
                                               const float* __restrict__ b2b,
                                               float* __restrict__ outpre, float* __restrict__ bnsum)
{
    __shared__ __align__(16) ushort_t W2T[16 * 168];
    int t = threadIdx.x;
    for (int i = t; i < 160 * 16; i += 256) { int k = i / 16, n = i % 16; W2T[n * 168 + k] = f2bf(w2b[i]); }
    __syncthreads();
    int w = t >> 6, L = t & 63, q = L >> 4, c = L & 15;
    const f32x4 zero = { 0.f, 0.f, 0.f, 0.f };
    float ps = 0.f, ps2 = 0.f;
    float bias = b2b[c];
    for (int rt = blockIdx.x * 4 + w; rt < 3125; rt += gridDim.x * 4) {
        int m = rt * 16 + c;
        f32x4 acc = zero;
        #pragma unroll
        for (int ks = 0; ks < 5; ks++) {
            bf16x8 a; __builtin_memcpy(&a, h2 + (size_t)m * 160 + ks * 32 + q * 8, 16);
            bf16x8 b; __builtin_memcpy(&b, &W2T[c * 168 + ks * 32 + q * 8], 16);
            acc = __builtin_amdgcn_mfma_f32_16x16x32_bf16(a, b, acc, 0, 0, 0);
        }
        #pragma unroll
        for (int r = 0; r < 4; r++) {
            float v = acc[r] + bias;
            outpre[(size_t)(rt * 16 + q * 4 + r) * 16 + c] = v;
            ps += v; ps2 += v * v;
        }
    }
    ps  += __shfl_xor(ps, 16);  ps  += __shfl_xor(ps, 32);
    ps2 += __shfl_xor(ps2, 16); ps2 += __shfl_xor(ps2, 32);
    if (q == 0) {
        unsafeAtomicAdd(&bnsum[c], ps);
        unsafeAtomicAdd(&bnsum[16 + c], ps2);
    }
}

// ---------------- K7: BatchNorm apply -> d_out (fp32) ----------------
__global__ __launch_bounds__(256) void k_bn(const float* __restrict__ outpre, const float* __restrict__ bnsum,
                                            const float* __restrict__ gamma, const float* __restrict__ beta,
                                            float* __restrict__ out)
{
    int i = blockIdx.x * 256 + threadIdx.x;
    int c = i & 15;
    float x = outpre[i];
    float mu = bnsum[c] * (1.f / N_NODES);
    float var = bnsum[16 + c] * (1.f / N_NODES) - mu * mu;
    out[i] = gamma[c] * (x - mu) * rsqrtf(var + 1e-5f) + beta[c];
}

// ---------------- launch ----------------
extern "C" void kernel_launch(void* const* d_in, const int* in_sizes, int n_in,
                              void* d_out, int out_size, void* d_ws, size_t ws_size,
                              hipStream_t stream) {
    const float* x_s  = (const float*)d_in[0];
    const float* x_t  = (const float*)d_in[1];
    const float* ea   = (const float*)d_in[2];
    const float* u    = (const float*)d_in[3];
    const float* w1a  = (const float*)d_in[4];
    const float* b1a  = (const float*)d_in[5];
    const float* w2a  = (const float*)d_in[6];
    const float* b2a  = (const float*)d_in[7];
    const float* w1b  = (const float*)d_in[8];
    const float* b1b  = (const float*)d_in[9];
    const float* w2b  = (const float*)d_in[10];
    const float* b2b  = (const float*)d_in[11];
    const float* gam  = (const float*)d_in[12];
    const float* bet  = (const float*)d_in[13];
    const int* eidx   = (const int*)d_in[14];
    const int* src = eidx;
    const int* tgt = eidx + N_EDGES;

    char* ws = (char*)d_ws;
    // workspace layout (bytes) — ws_size >= 138,001,536 proven (round 5 ran staged path).
    //   cnt     [0        , 262,144)   int[50000], zeroed; live k_hist -> k_node
    //   rowptr  [262,144  , 524,288)   int[50000]; live k_scan_add -> k_node
    //   cursor  [524,288  , 786,432)   int[50000]; live scan -> k_mlp_scatter
    //   blksum  [786,432  , 787,456)   int[256]
    //   bnsum   [787,456  , 787,584)   float[32]  (zeroed by k_node)
    //   outpre  [787,584  , 3,987,584) float[800000]
    //   rec     [4,194,304, 106,594,304) fp16[1.6M*32]; live k_mlp_scatter -> k_node
    //   hcat    [106,594,304, 122,594,304) bf16[50000*160]; live k_node -> k_gemm1
    //   h2      [4,194,304, 20,194,304) bf16[50000*160] OVERLAY rec (dead after k_node)
    const size_t OFF_CNT    = 0;
    const size_t OFF_ROWPTR = 262144;
    const size_t OFF_CURSOR = 524288;
    const size_t OFF_BLKSUM = 786432;
    const size_t OFF_BNSUM  = 787456;
    const size_t OFF_OUTPRE = 787584;
    const size_t OFF_REC    = 4194304;
    const size_t OFF_HCAT   = 106594304;
    const size_t OFF_H2     = 4194304;

    int*   cnt     = (int*)(ws + OFF_CNT);
    int*   rowptr  = (int*)(ws + OFF_ROWPTR);
    int*   cursor  = (int*)(ws + OFF_CURSOR);
    int*   blksum  = (int*)(ws + OFF_BLKSUM);
    float* bnsum   = (float*)(ws + OFF_BNSUM);
    float* outpre  = (float*)(ws + OFF_OUTPRE);
    f16*   rec     = (f16*)(ws + OFF_REC);
    ushort_t* hcat = (ushort_t*)(ws + OFF_HCAT);
    ushort_t* h2   = (ushort_t*)(ws + OFF_H2);

    (void)hipMemsetAsync(cnt, 0, 200000, stream);   // only cnt needs zeroing now

    k_hist<<<(N_EDGES + 255) / 256, 256, 0, stream>>>(src, cnt);
    k_scan_chunk<<<NCHUNK, 256, 0, stream>>>(cnt, cursor, blksum);
    k_scan_block<<<1, 256, 0, stream>>>(blksum);
    k_scan_add<<<NCHUNK, 256, 0, stream>>>(cursor, blksum, rowptr);
    k_mlp_scatter<<<2048, 256, 0, stream>>>(x_t, ea, w1a, b1a, w2a, b2a, src, tgt, cursor, rec);
    k_node<<<N_NODES / 4, 256, 0, stream>>>(rec, rowptr, cnt, x_s, u, hcat, bnsum);
    k_gemm1<<<1024, 256, 0, stream>>>(hcat, w1b, b1b, h2);
    k_gemm2<<<512, 256, 0, stream>>>(h2, w2b, b2b, outpre, bnsum);
    k_bn<<<(N_NODES * 16) / 256, 256, 0, stream>>>(outpre, bnsum, gam, bet, (float*)d_out);
}